// Round 1
// baseline (1612.677 us; speedup 1.0000x reference)
//
#include <hip/hip_runtime.h>
#include <hip/hip_bf16.h>
#include <cstdint>
#include <cstddef>

// Problem constants (fixed by setup_inputs; groupsize==256 is d_in[4] scalar)
#define M_TOK 8192        // B*S = 4*2048 tokens
#define K_IN  4096        // IN
#define N_OUT 11008       // OUT
#define GRP   256
#define NGRP  (K_IN / GRP)   // 16

typedef float f32x4   __attribute__((ext_vector_type(4)));
typedef short bf16x8  __attribute__((ext_vector_type(8)));  // 8 bf16 = 4 VGPRs (guide §3)

// fp32 -> bf16 round-to-nearest-even (no NaN inputs here)
__device__ inline unsigned short f2bf(float f) {
    uint32_t u = __float_as_uint(f);
    uint32_t r = (u + 0x7fffu + ((u >> 16) & 1u)) >> 16;
    return (unsigned short)r;
}

// ---------------------------------------------------------------------------
// Kernel 1: per-token dynamic int8 fake-quant -> bf16, bit-exact to reference
// (IEEE div, rintf = round-half-even = jnp.round, identical op order).
// One block (256 threads) per token; each thread owns 16 elems as 4x float4.
// ---------------------------------------------------------------------------
__global__ __launch_bounds__(256)
void quant_kernel(const float* __restrict__ x, unsigned short* __restrict__ qx)
{
    const int t   = blockIdx.x;
    const int tid = threadIdx.x;
    const float* xr = x + (size_t)t * K_IN;

    float4 v[4];
    float mn = 0.0f, mx = 0.0f;   // init 0 implements min(.,0)/max(.,0)
    #pragma unroll
    for (int j = 0; j < 4; ++j) {
        v[j] = ((const float4*)xr)[j * 256 + tid];
        mn = fminf(mn, fminf(fminf(v[j].x, v[j].y), fminf(v[j].z, v[j].w)));
        mx = fmaxf(mx, fmaxf(fmaxf(v[j].x, v[j].y), fmaxf(v[j].z, v[j].w)));
    }
    // wave64 butterfly reduce
    #pragma unroll
    for (int off = 32; off > 0; off >>= 1) {
        mn = fminf(mn, __shfl_xor(mn, off));
        mx = fmaxf(mx, __shfl_xor(mx, off));
    }
    __shared__ float smn[4], smx[4];
    if ((tid & 63) == 0) { smn[tid >> 6] = mn; smx[tid >> 6] = mx; }
    __syncthreads();
    mn = fminf(fminf(smn[0], smn[1]), fminf(smn[2], smn[3]));
    mx = fmaxf(fmaxf(smx[0], smx[1]), fmaxf(smx[2], smx[3]));

    const float scale = fmaxf((mx - mn) / 255.0f, 1.1920929e-7f);  // FLT_EPSILON
    const float dmin  = mn / scale;
    const float dmax  = mx / scale;
    float zp = (((-128.0f + dmin) + (127.0f + dmax)) > 0.0f) ? (-128.0f - dmin)
                                                             : (127.0f - dmax);
    zp = rintf(fminf(fmaxf(zp, -128.0f), 127.0f));

    unsigned short* qr = qx + (size_t)t * K_IN;
    #pragma unroll
    for (int j = 0; j < 4; ++j) {
        float q0 = fminf(fmaxf(rintf(v[j].x / scale) + zp, -128.0f), 127.0f);
        float q1 = fminf(fmaxf(rintf(v[j].y / scale) + zp, -128.0f), 127.0f);
        float q2 = fminf(fmaxf(rintf(v[j].z / scale) + zp, -128.0f), 127.0f);
        float q3 = fminf(fmaxf(rintf(v[j].w / scale) + zp, -128.0f), 127.0f);
        ushort4 o;
        o.x = f2bf((q0 - zp) * scale);
        o.y = f2bf((q1 - zp) * scale);
        o.z = f2bf((q2 - zp) * scale);
        o.w = f2bf((q3 - zp) * scale);
        ((ushort4*)qr)[j * 256 + tid] = o;
    }
}

// ---------------------------------------------------------------------------
// Kernel 2: groupwise int4 dequant of weights -> bf16, [N,K] row-major (B^T).
// 4 elems/thread (one int4 load, one ushort4 store); group = k>>8.
// ---------------------------------------------------------------------------
__global__ __launch_bounds__(256)
void wprep_kernel(const int* __restrict__ w, const float* __restrict__ scales,
                  const float* __restrict__ zeros, unsigned short* __restrict__ wdq)
{
    const size_t idx  = (size_t)blockIdx.x * 256 + threadIdx.x;
    const size_t base = idx * 4;                       // element index
    const int o = (int)(base >> 12);                   // /4096
    const int k = (int)(base & 4095);
    const int g = k >> 8;                              // /GRP
    const float s = scales[o * NGRP + g];
    const float z = zeros [o * NGRP + g];
    const int4 wi = *(const int4*)(w + base);
    ushort4 out;
    out.x = f2bf(((float)wi.x - z) * s);
    out.y = f2bf(((float)wi.y - z) * s);
    out.z = f2bf(((float)wi.z - z) * s);
    out.w = f2bf(((float)wi.w - z) * s);
    *(ushort4*)(wdq + base) = out;
}

// ---------------------------------------------------------------------------
// Kernel 3: bf16 GEMM, m97 recipe. C[M,N] = A[M,K] * B[N,K]^T.
// 128x128 block tile, BK=64, 4 waves (2x2), wave = 4x4 of 16x16x32 MFMA.
// global_load_lds width=16 staging; row-major unpadded LDS tiles (required
// by the wave-uniform-base + lane*16 LDS addressing of global_load_lds).
// ---------------------------------------------------------------------------
__global__ __launch_bounds__(256)
void gemm_kernel(const unsigned short* __restrict__ A,   // [M_TOK, K_IN] bf16
                 const unsigned short* __restrict__ B,   // [N_OUT, K_IN] bf16
                 float* __restrict__ C)                  // [M_TOK, N_OUT] f32
{
    __shared__ unsigned short As[128 * 64];  // 16 KiB
    __shared__ unsigned short Bs[128 * 64];  // 16 KiB

    const int tid  = threadIdx.x;
    const int lane = tid & 63;
    const int wave = tid >> 6;
    const int wm = (wave >> 1) * 64;     // wave row offset in tile
    const int wn = (wave & 1)  * 64;     // wave col offset in tile
    const int bm = blockIdx.y * 128;
    const int bn = blockIdx.x * 128;

    const int lrow = lane & 15;          // fragment m/n index
    const int lk   = (lane >> 4) * 8;    // fragment k offset (verified layout)

    f32x4 acc[4][4] = {};

    for (int k0 = 0; k0 < K_IN; k0 += 64) {
        // stage A tile: 4 issues x 256 threads x 16B = 16 KiB
        #pragma unroll
        for (int i = 0; i < 4; ++i) {
            int chunk = i * 256 + tid;          // 16B chunk id
            int row = chunk >> 3;               // 8 chunks per 64-elem row
            int col = (chunk & 7) << 3;
            __builtin_amdgcn_global_load_lds(
                (const __attribute__((address_space(1))) void*)(A + (size_t)(bm + row) * K_IN + k0 + col),
                (__attribute__((address_space(3))) void*)(As + (size_t)chunk * 8),
                16, 0, 0);
        }
        #pragma unroll
        for (int i = 0; i < 4; ++i) {
            int chunk = i * 256 + tid;
            int row = chunk >> 3;
            int col = (chunk & 7) << 3;
            __builtin_amdgcn_global_load_lds(
                (const __attribute__((address_space(1))) void*)(B + (size_t)(bn + row) * K_IN + k0 + col),
                (__attribute__((address_space(3))) void*)(Bs + (size_t)chunk * 8),
                16, 0, 0);
        }
        __syncthreads();   // compiler emits vmcnt(0) drain before barrier

        #pragma unroll
        for (int kk = 0; kk < 64; kk += 32) {
            bf16x8 af[4], bfr[4];
            #pragma unroll
            for (int mi = 0; mi < 4; ++mi)
                af[mi] = *(const bf16x8*)(As + (wm + mi * 16 + lrow) * 64 + kk + lk);
            #pragma unroll
            for (int ni = 0; ni < 4; ++ni)
                bfr[ni] = *(const bf16x8*)(Bs + (wn + ni * 16 + lrow) * 64 + kk + lk);
            #pragma unroll
            for (int mi = 0; mi < 4; ++mi)
                #pragma unroll
                for (int ni = 0; ni < 4; ++ni)
                    acc[mi][ni] = __builtin_amdgcn_mfma_f32_16x16x32_bf16(
                        af[mi], bfr[ni], acc[mi][ni], 0, 0, 0);
        }
        __syncthreads();
    }

    // Epilogue: C/D layout (verified m89/m91): col = lane&15, row = (lane>>4)*4 + reg
    const int ccol = lane & 15;
    const int crow = (lane >> 4) * 4;
    #pragma unroll
    for (int mi = 0; mi < 4; ++mi) {
        #pragma unroll
        for (int ni = 0; ni < 4; ++ni) {
            f32x4 v = acc[mi][ni];
            const int m0 = bm + wm + mi * 16 + crow;
            const int n0 = bn + wn + ni * 16 + ccol;
            #pragma unroll
            for (int r = 0; r < 4; ++r)
                C[(size_t)(m0 + r) * N_OUT + n0] = v[r];
        }
    }
}

// ---------------------------------------------------------------------------
extern "C" void kernel_launch(void* const* d_in, const int* in_sizes, int n_in,
                              void* d_out, int out_size, void* d_ws, size_t ws_size,
                              hipStream_t stream)
{
    const float* x      = (const float*)d_in[0];  // [4,2048,4096] f32
    const int*   w      = (const int*)  d_in[1];  // [11008,4096] int32 in [-8,7]
    const float* scales = (const float*)d_in[2];  // [11008,16] f32
    const float* zeros  = (const float*)d_in[3];  // [11008,16] f32
    // d_in[4] = groupsize (256), fixed for this problem.
    float* out = (float*)d_out;                   // [8192,11008] f32

    // ws layout: qx bf16 [M,K] (64 MiB) | wdq bf16 [N,K] (86 MiB) -> 150 MiB total
    unsigned short* qx  = (unsigned short*)d_ws;
    unsigned short* wdq = qx + (size_t)M_TOK * K_IN;

    quant_kernel<<<M_TOK, 256, 0, stream>>>(x, qx);
    wprep_kernel<<<(int)(((size_t)N_OUT * K_IN / 4) / 256), 256, 0, stream>>>(w, scales, zeros, wdq);
    gemm_kernel<<<dim3(N_OUT / 128, M_TOK / 128), 256, 0, stream>>>(qx, wdq, out);
}

// Round 2
// 1530.673 us; speedup vs baseline: 1.0536x; 1.0536x over previous
//
#include <hip/hip_runtime.h>
#include <hip/hip_bf16.h>
#include <cstdint>
#include <cstddef>

// Problem constants (fixed by setup_inputs; groupsize==256 is d_in[4] scalar)
#define M_TOK 8192        // B*S = 4*2048 tokens
#define K_IN  4096        // IN
#define N_OUT 11008       // OUT
#define GRP   256
#define NGRP  (K_IN / GRP)   // 16

typedef float f32x4   __attribute__((ext_vector_type(4)));
typedef short bf16x8  __attribute__((ext_vector_type(8)));  // 8 bf16 = 4 VGPRs

// fp32 -> bf16 round-to-nearest-even (no NaN inputs here)
__device__ inline unsigned short f2bf(float f) {
    uint32_t u = __float_as_uint(f);
    uint32_t r = (u + 0x7fffu + ((u >> 16) & 1u)) >> 16;
    return (unsigned short)r;
}

// ---------------------------------------------------------------------------
// Kernel 1: per-token dynamic int8 fake-quant -> bf16, bit-exact to reference
// ---------------------------------------------------------------------------
__global__ __launch_bounds__(256)
void quant_kernel(const float* __restrict__ x, unsigned short* __restrict__ qx)
{
    const int t   = blockIdx.x;
    const int tid = threadIdx.x;
    const float* xr = x + (size_t)t * K_IN;

    float4 v[4];
    float mn = 0.0f, mx = 0.0f;   // init 0 implements min(.,0)/max(.,0)
    #pragma unroll
    for (int j = 0; j < 4; ++j) {
        v[j] = ((const float4*)xr)[j * 256 + tid];
        mn = fminf(mn, fminf(fminf(v[j].x, v[j].y), fminf(v[j].z, v[j].w)));
        mx = fmaxf(mx, fmaxf(fmaxf(v[j].x, v[j].y), fmaxf(v[j].z, v[j].w)));
    }
    #pragma unroll
    for (int off = 32; off > 0; off >>= 1) {
        mn = fminf(mn, __shfl_xor(mn, off));
        mx = fmaxf(mx, __shfl_xor(mx, off));
    }
    __shared__ float smn[4], smx[4];
    if ((tid & 63) == 0) { smn[tid >> 6] = mn; smx[tid >> 6] = mx; }
    __syncthreads();
    mn = fminf(fminf(smn[0], smn[1]), fminf(smn[2], smn[3]));
    mx = fmaxf(fmaxf(smx[0], smx[1]), fmaxf(smx[2], smx[3]));

    const float scale = fmaxf((mx - mn) / 255.0f, 1.1920929e-7f);  // FLT_EPSILON
    const float dmin  = mn / scale;
    const float dmax  = mx / scale;
    float zp = (((-128.0f + dmin) + (127.0f + dmax)) > 0.0f) ? (-128.0f - dmin)
                                                             : (127.0f - dmax);
    zp = rintf(fminf(fmaxf(zp, -128.0f), 127.0f));

    unsigned short* qr = qx + (size_t)t * K_IN;
    #pragma unroll
    for (int j = 0; j < 4; ++j) {
        float q0 = fminf(fmaxf(rintf(v[j].x / scale) + zp, -128.0f), 127.0f);
        float q1 = fminf(fmaxf(rintf(v[j].y / scale) + zp, -128.0f), 127.0f);
        float q2 = fminf(fmaxf(rintf(v[j].z / scale) + zp, -128.0f), 127.0f);
        float q3 = fminf(fmaxf(rintf(v[j].w / scale) + zp, -128.0f), 127.0f);
        ushort4 o;
        o.x = f2bf((q0 - zp) * scale);
        o.y = f2bf((q1 - zp) * scale);
        o.z = f2bf((q2 - zp) * scale);
        o.w = f2bf((q3 - zp) * scale);
        ((ushort4*)qr)[j * 256 + tid] = o;
    }
}

// ---------------------------------------------------------------------------
// Kernel 2: groupwise int4 dequant of weights -> bf16, [N,K] row-major (B^T).
// ---------------------------------------------------------------------------
__global__ __launch_bounds__(256)
void wprep_kernel(const int* __restrict__ w, const float* __restrict__ scales,
                  const float* __restrict__ zeros, unsigned short* __restrict__ wdq)
{
    const size_t idx  = (size_t)blockIdx.x * 256 + threadIdx.x;
    const size_t base = idx * 4;                       // element index
    const int o = (int)(base >> 12);                   // /4096
    const int k = (int)(base & 4095);
    const int g = k >> 8;                              // /GRP
    const float s = scales[o * NGRP + g];
    const float z = zeros [o * NGRP + g];
    const int4 wi = *(const int4*)(w + base);
    ushort4 out;
    out.x = f2bf(((float)wi.x - z) * s);
    out.y = f2bf(((float)wi.y - z) * s);
    out.z = f2bf(((float)wi.z - z) * s);
    out.w = f2bf(((float)wi.w - z) * s);
    *(ushort4*)(wdq + base) = out;
}

// ---------------------------------------------------------------------------
// Kernel 3: bf16 GEMM, m97 recipe + XOR-swizzled LDS to kill bank conflicts.
// C[M,N] = A[M,K] * B[N,K]^T. 128x128 tile, BK=64, 4 waves (2x2), wave = 4x4
// of 16x16x32 MFMA.
//
// LDS layout: tile row r occupies 8 chunks of 16B; LDS slot (r, cc) holds
// GLOBAL column chunk cc ^ (r&7). Staging keeps the mandatory dest =
// uniform-base + lane*16B order (we permute the global source address, which
// is per-lane). Fragment reads XOR the chunk index back. Within each 8-lane
// LDS phase, rows 0..7 then map to 8 distinct 16B chunks = all 32 banks ->
// conflict-free (rows 8..15 alias 2-way, which is free per m136).
// ---------------------------------------------------------------------------
__global__ __launch_bounds__(256)
void gemm_kernel(const unsigned short* __restrict__ A,   // [M_TOK, K_IN] bf16
                 const unsigned short* __restrict__ B,   // [N_OUT, K_IN] bf16
                 float* __restrict__ C)                  // [M_TOK, N_OUT] f32
{
    __shared__ unsigned short As[128 * 64];  // 16 KiB
    __shared__ unsigned short Bs[128 * 64];  // 16 KiB

    const int tid  = threadIdx.x;
    const int lane = tid & 63;
    const int wave = tid >> 6;
    const int wm = (wave >> 1) * 64;     // wave row offset in tile
    const int wn = (wave & 1)  * 64;     // wave col offset in tile
    const int bm = blockIdx.y * 128;
    const int bn = blockIdx.x * 128;

    const int lrow = lane & 15;          // fragment m/n index
    const int lk   = (lane >> 4) * 8;    // fragment k elem offset (pre-swizzle)
    const int sw   = lrow & 7;           // swizzle selector (row&7 == lrow&7 here)

    f32x4 acc[4][4] = {};

    for (int k0 = 0; k0 < K_IN; k0 += 64) {
        // stage A tile: 4 issues x 256 threads x 16B = 16 KiB
        #pragma unroll
        for (int i = 0; i < 4; ++i) {
            int chunk = i * 256 + tid;          // LDS 16B-chunk id (dest fixed)
            int row = chunk >> 3;               // 8 chunks per 64-elem row
            int cc  = chunk & 7;                // LDS column chunk
            int gc  = cc ^ (row & 7);           // global column chunk (swizzle)
            __builtin_amdgcn_global_load_lds(
                (const __attribute__((address_space(1))) void*)(A + (size_t)(bm + row) * K_IN + k0 + (gc << 3)),
                (__attribute__((address_space(3))) void*)(As + (size_t)chunk * 8),
                16, 0, 0);
        }
        #pragma unroll
        for (int i = 0; i < 4; ++i) {
            int chunk = i * 256 + tid;
            int row = chunk >> 3;
            int cc  = chunk & 7;
            int gc  = cc ^ (row & 7);
            __builtin_amdgcn_global_load_lds(
                (const __attribute__((address_space(1))) void*)(B + (size_t)(bn + row) * K_IN + k0 + (gc << 3)),
                (__attribute__((address_space(3))) void*)(Bs + (size_t)chunk * 8),
                16, 0, 0);
        }
        __syncthreads();

        #pragma unroll
        for (int kk = 0; kk < 64; kk += 32) {
            const int coff = ((((kk + lk) >> 3) ^ sw) << 3);  // swizzled elem offset
            bf16x8 af[4], bfr[4];
            #pragma unroll
            for (int mi = 0; mi < 4; ++mi)
                af[mi] = *(const bf16x8*)(As + (wm + mi * 16 + lrow) * 64 + coff);
            #pragma unroll
            for (int ni = 0; ni < 4; ++ni)
                bfr[ni] = *(const bf16x8*)(Bs + (wn + ni * 16 + lrow) * 64 + coff);
            #pragma unroll
            for (int mi = 0; mi < 4; ++mi)
                #pragma unroll
                for (int ni = 0; ni < 4; ++ni)
                    acc[mi][ni] = __builtin_amdgcn_mfma_f32_16x16x32_bf16(
                        af[mi], bfr[ni], acc[mi][ni], 0, 0, 0);
        }
        __syncthreads();
    }

    // Epilogue: C/D layout (verified m89/m91): col = lane&15, row = (lane>>4)*4 + reg
    const int ccol = lane & 15;
    const int crow = (lane >> 4) * 4;
    #pragma unroll
    for (int mi = 0; mi < 4; ++mi) {
        #pragma unroll
        for (int ni = 0; ni < 4; ++ni) {
            f32x4 v = acc[mi][ni];
            const int m0 = bm + wm + mi * 16 + crow;
            const int n0 = bn + wn + ni * 16 + ccol;
            #pragma unroll
            for (int r = 0; r < 4; ++r)
                C[(size_t)(m0 + r) * N_OUT + n0] = v[r];
        }
    }
}

// ---------------------------------------------------------------------------
extern "C" void kernel_launch(void* const* d_in, const int* in_sizes, int n_in,
                              void* d_out, int out_size, void* d_ws, size_t ws_size,
                              hipStream_t stream)
{
    const float* x      = (const float*)d_in[0];  // [4,2048,4096] f32
    const int*   w      = (const int*)  d_in[1];  // [11008,4096] int32 in [-8,7]
    const float* scales = (const float*)d_in[2];  // [11008,16] f32
    const float* zeros  = (const float*)d_in[3];  // [11008,16] f32
    float* out = (float*)d_out;                   // [8192,11008] f32

    unsigned short* qx  = (unsigned short*)d_ws;
    unsigned short* wdq = qx + (size_t)M_TOK * K_IN;

    quant_kernel<<<M_TOK, 256, 0, stream>>>(x, qx);
    wprep_kernel<<<(int)(((size_t)N_OUT * K_IN / 4) / 256), 256, 0, stream>>>(w, scales, zeros, wdq);
    gemm_kernel<<<dim3(N_OUT / 128, M_TOK / 128), 256, 0, stream>>>(qx, wdq, out);
}